// Round 1
// baseline (406.227 us; speedup 1.0000x reference)
//
#include <hip/hip_runtime.h>
#include <stdint.h>

typedef __bf16 bf16x8 __attribute__((ext_vector_type(8)));
typedef float  f32x4  __attribute__((ext_vector_type(4)));
typedef unsigned short u16x8 __attribute__((ext_vector_type(8)));

__device__ __forceinline__ unsigned short f2bf(float f) {
    union { float f; unsigned int u; } v; v.f = f;
    unsigned int u = v.u;
    return (unsigned short)((u + 0x7FFFu + ((u >> 16) & 1u)) >> 16);
}

// ---------------------------------------------------------------------------
// Kernel 1: cast x (fp32) -> bf16 A[M][K]. 8 elems/thread, 16B stores.
// ---------------------------------------------------------------------------
__global__ void cast_x_kernel(const float4* __restrict__ X,
                              u16x8* __restrict__ A, int n8) {
    int i = blockIdx.x * blockDim.x + threadIdx.x;
    if (i < n8) {
        float4 v0 = X[i * 2];
        float4 v1 = X[i * 2 + 1];
        u16x8 o;
        o[0] = f2bf(v0.x); o[1] = f2bf(v0.y); o[2] = f2bf(v0.z); o[3] = f2bf(v0.w);
        o[4] = f2bf(v1.x); o[5] = f2bf(v1.y); o[6] = f2bf(v1.z); o[7] = f2bf(v1.w);
        A[i] = o;
    }
}

// ---------------------------------------------------------------------------
// Kernel 2: FWHT each row of W (len 2048), scale 1/sqrt(2048), emit bf16.
// H symmetric+orthogonal: (xH/vn) W^T == x (W H/vn)^T.
// ---------------------------------------------------------------------------
__global__ void fwht_w_kernel(const float* __restrict__ W,
                              unsigned short* __restrict__ Bt) {
    const int n = 2048;
    __shared__ float buf[2048];
    const float* src = W + (size_t)blockIdx.x * n;
    for (int i = threadIdx.x; i < n; i += 256) buf[i] = src[i];
    __syncthreads();
    for (int len = 1; len < n; len <<= 1) {
        for (int j = threadIdx.x; j < n / 2; j += 256) {
            int idx = ((j & ~(len - 1)) << 1) | (j & (len - 1));
            float a = buf[idx], b = buf[idx + len];
            buf[idx]       = a + b;
            buf[idx + len] = a - b;
        }
        __syncthreads();
    }
    const float scale = 0.02209708691207961f; // 1/sqrt(2048)
    unsigned short* dst = Bt + (size_t)blockIdx.x * n;
    for (int i = threadIdx.x; i < n; i += 256) dst[i] = f2bf(buf[i] * scale);
}

// ---------------------------------------------------------------------------
// Kernel 3 (R5): C[M][N] = A[M][K]*B[N][K]^T + bias, bf16 MFMA 16x16x32.
//
// 256x256 tile, 8 waves (2Mx4N, 512 thr), BK=32, 4-slab LDS ring (128 KiB).
// Pipeline (T3+T4): while computing tile t, stage tile t+3; one counted
// s_waitcnt vmcnt(8) per tile (never 0 in steady state) => tile t+1's loads
// confirmed, tiles t+2/t+3 stay in flight across the barrier. Slab (t+3)&3
// was last READ during tile t-1 (reads drained before the preceding
// barrier), so staging it during tile t is WAR-safe.
// T2 swizzle: byte ^= ((row>>1)&3)<<4 spreads 64B-stride rows over all 32
// banks (was 8-way conflict -> SQ_LDS_BANK_CONFLICT 1.7e7). Applied on the
// global_load_lds SOURCE address (linear LDS dest, rule 21) and the same
// XOR on the ds_read side.
// T5: s_setprio(1) around each 16-MFMA cluster.
// Raw s_barrier + asm("":::"memory") fences so memory ops can't cross
// barriers at compile time (no __syncthreads => no vmcnt(0) drain).
// ---------------------------------------------------------------------------
constexpr int GK = 2048;       // K (fixed by problem)
constexpr int GN = 2048;       // N
constexpr int NT = GK / 32;    // 64 k-tiles

__global__ __launch_bounds__(512, 2) void had_gemm_kernel(
    const unsigned short* __restrict__ A,   // [M][K] bf16
    const unsigned short* __restrict__ B,   // [N][K] bf16 (W')
    const float* __restrict__ bias,         // [N]
    float* __restrict__ C)                  // [M][N] fp32
{
    __shared__ __attribute__((aligned(16))) unsigned short As[4][256 * 32];
    __shared__ __attribute__((aligned(16))) unsigned short Bs[4][256 * 32];

    const int tid  = threadIdx.x;
    const int lane = tid & 63;
    const int wave = tid >> 6;      // 0..7
    const int wm   = wave & 1;      // row half  (128 rows)
    const int wn   = wave >> 1;     // col quarter (64 cols)
    const int l16  = lane & 15;
    const int quad = lane >> 4;
    const int m0 = blockIdx.y * 256;
    const int n0 = blockIdx.x * 256;

    f32x4 acc[8][4] = {};

    // ---- staging geometry: inst i covers rows [i*128, i*128+128) of the
    // tile, thread -> row = i*128 + tid/4, 16B chunk (tid&3) of the 64B
    // k-slice. Source col pre-swizzled; LDS dest linear (wave base+lane*16).
    const int srow = tid >> 2;
    const int swzc = ((tid & 3) * 16) ^ (((srow >> 1) & 3) << 4);
    const char* gA0 = (const char*)(A + (size_t)(m0 + srow) * GK) + swzc;
    const char* gA1 = (const char*)(A + (size_t)(m0 + 128 + srow) * GK) + swzc;
    const char* gB0 = (const char*)(B + (size_t)(n0 + srow) * GK) + swzc;
    const char* gB1 = (const char*)(B + (size_t)(n0 + 128 + srow) * GK) + swzc;
    // ((srow+128)>>1)&3 == (srow>>1)&3, so swzc is valid for both insts.

#define STAGE_A(t_) { const int sl_ = (t_) & 3;                                   \
    __builtin_amdgcn_global_load_lds(                                             \
        (const __attribute__((address_space(1))) void*)(gA0 + (t_) * 64),         \
        (__attribute__((address_space(3))) void*)(&As[sl_][wave * 512]), 16, 0, 0);\
    __builtin_amdgcn_global_load_lds(                                             \
        (const __attribute__((address_space(1))) void*)(gA1 + (t_) * 64),         \
        (__attribute__((address_space(3))) void*)(&As[sl_][4096 + wave * 512]), 16, 0, 0); }
#define STAGE_B(t_) { const int sl_ = (t_) & 3;                                   \
    __builtin_amdgcn_global_load_lds(                                             \
        (const __attribute__((address_space(1))) void*)(gB0 + (t_) * 64),         \
        (__attribute__((address_space(3))) void*)(&Bs[sl_][wave * 512]), 16, 0, 0);\
    __builtin_amdgcn_global_load_lds(                                             \
        (const __attribute__((address_space(1))) void*)(gB1 + (t_) * 64),         \
        (__attribute__((address_space(3))) void*)(&Bs[sl_][4096 + wave * 512]), 16, 0, 0); }

    // ---- fragment read offsets (same XOR as staging source) ----
    const int arow = wm * 128 + l16;
    const int brow = wn * 64 + l16;
    const int sw   = ((l16 >> 1) & 3) << 4;   // row bits 1-2 come from l16
    const unsigned aoff = (unsigned)(arow * 64 + quad * 16) ^ sw;
    const unsigned boff = (unsigned)(brow * 64 + quad * 16) ^ sw;
    const char* sabase = (const char*)&As[0][0];
    const char* sbbase = (const char*)&Bs[0][0];

    // ---- prologue: stage tiles 0..2 (12 loads), confirm tile 0 ----
    STAGE_A(0) STAGE_B(0) asm volatile("" ::: "memory");
    STAGE_A(1) STAGE_B(1) asm volatile("" ::: "memory");
    STAGE_A(2) STAGE_B(2)
    asm volatile("s_waitcnt vmcnt(8)" ::: "memory");   // oldest 4 = tile 0 done
    __builtin_amdgcn_s_barrier();
    asm volatile("" ::: "memory");

    for (int t = 0; t < NT; ++t) {
        const char* sa = sabase + (size_t)(t & 3) * 16384;
        const char* sb = sbbase + (size_t)(t & 3) * 16384;
        bf16x8 af[4], bfr[4];

        // ================= phase 0: rows 0-63, all B frags =================
        if (t + 3 < NT) STAGE_A(t + 3);
        #pragma unroll
        for (int j = 0; j < 4; ++j)
            bfr[j] = *(const bf16x8*)(sb + (boff + j * 1024u));
        #pragma unroll
        for (int i = 0; i < 4; ++i)
            af[i] = *(const bf16x8*)(sa + (aoff + i * 1024u));
        asm volatile("" ::: "memory");
        __builtin_amdgcn_s_barrier();
        __builtin_amdgcn_s_setprio(1);
        #pragma unroll
        for (int i = 0; i < 4; ++i)
            #pragma unroll
            for (int j = 0; j < 4; ++j)
                acc[i][j] = __builtin_amdgcn_mfma_f32_16x16x32_bf16(
                    af[i], bfr[j], acc[i][j], 0, 0, 0);
        __builtin_amdgcn_s_setprio(0);
        __builtin_amdgcn_s_barrier();
        asm volatile("" ::: "memory");

        // ================= phase 1: rows 64-127 ============================
        if (t + 3 < NT) STAGE_B(t + 3);
        #pragma unroll
        for (int i = 0; i < 4; ++i)
            af[i] = *(const bf16x8*)(sa + (aoff + (4 + i) * 1024u));
        asm volatile("" ::: "memory");
        __builtin_amdgcn_s_barrier();
        __builtin_amdgcn_s_setprio(1);
        #pragma unroll
        for (int i = 0; i < 4; ++i)
            #pragma unroll
            for (int j = 0; j < 4; ++j)
                acc[4 + i][j] = __builtin_amdgcn_mfma_f32_16x16x32_bf16(
                    af[i], bfr[j], acc[4 + i][j], 0, 0, 0);
        __builtin_amdgcn_s_setprio(0);

        // tile end: counted wait (tile t+1 confirmed; t+2/t+3 stay in flight)
        if (t < NT - 3)       { asm volatile("s_waitcnt vmcnt(8)" ::: "memory"); }
        else if (t == NT - 3) { asm volatile("s_waitcnt vmcnt(4)" ::: "memory"); }
        else if (t == NT - 2) { asm volatile("s_waitcnt vmcnt(0)" ::: "memory"); }
        __builtin_amdgcn_s_barrier();
        asm volatile("" ::: "memory");
    }
#undef STAGE_A
#undef STAGE_B

    // ---- epilogue: C/D layout col=lane&15, row=quad*4+reg (m89-verified) ----
    float bv[4];
    #pragma unroll
    for (int j = 0; j < 4; ++j) bv[j] = bias[n0 + wn * 64 + j * 16 + l16];

    #pragma unroll
    for (int i = 0; i < 8; ++i) {
        #pragma unroll
        for (int r = 0; r < 4; ++r) {
            int row = m0 + wm * 128 + i * 16 + quad * 4 + r;
            float* cp = C + (size_t)row * GN + (n0 + wn * 64 + l16);
            #pragma unroll
            for (int j = 0; j < 4; ++j)
                cp[j * 16] = acc[i][j][r] + bv[j];
        }
    }
}

// ---------------------------------------------------------------------------
extern "C" void kernel_launch(void* const* d_in, const int* in_sizes, int n_in,
                              void* d_out, int out_size, void* d_ws, size_t ws_size,
                              hipStream_t stream) {
    const float* x = (const float*)d_in[0];  // [4,4096,2048] fp32
    const float* W = (const float*)d_in[1];  // [2048,2048]  fp32
    const float* b = (const float*)d_in[2];  // [2048]       fp32
    float* out = (float*)d_out;              // [4,4096,2048] fp32

    const int d = in_sizes[2];          // 2048
    const int M = in_sizes[0] / d;      // 16384
    const int N = d, K = d;

    // Workspace: A bf16 [M][K] (64 MB) + W' bf16 [N][K] (8 MB)
    unsigned short* A_ws  = (unsigned short*)d_ws;
    unsigned short* Bt_ws = A_ws + (size_t)M * K;

    int n8 = in_sizes[0] / 8;
    cast_x_kernel<<<(n8 + 255) / 256, 256, 0, stream>>>(
        (const float4*)x, (u16x8*)A_ws, n8);

    fwht_w_kernel<<<N, 256, 0, stream>>>(W, Bt_ws);

    dim3 grid(N / 256, M / 256);  // (8, 64) = 512 blocks
    had_gemm_kernel<<<grid, 512, 0, stream>>>(A_ws, Bt_ws, b, out);
}

// Round 3
// 393.983 us; speedup vs baseline: 1.0311x; 1.0311x over previous
//
#include <hip/hip_runtime.h>
#include <stdint.h>

typedef __bf16 bf16x8 __attribute__((ext_vector_type(8)));
typedef float  f32x4  __attribute__((ext_vector_type(4)));
typedef unsigned short u16x8 __attribute__((ext_vector_type(8)));

__device__ __forceinline__ unsigned short f2bf(float f) {
    union { float f; unsigned int u; } v; v.f = f;
    unsigned int u = v.u;
    return (unsigned short)((u + 0x7FFFu + ((u >> 16) & 1u)) >> 16);
}

// ---------------------------------------------------------------------------
// Kernel 1: cast x (fp32) -> bf16 A[M][K]. 8 elems/thread, 16B stores.
// ---------------------------------------------------------------------------
__global__ void cast_x_kernel(const float4* __restrict__ X,
                              u16x8* __restrict__ A, int n8) {
    int i = blockIdx.x * blockDim.x + threadIdx.x;
    if (i < n8) {
        float4 v0 = X[i * 2];
        float4 v1 = X[i * 2 + 1];
        u16x8 o;
        o[0] = f2bf(v0.x); o[1] = f2bf(v0.y); o[2] = f2bf(v0.z); o[3] = f2bf(v0.w);
        o[4] = f2bf(v1.x); o[5] = f2bf(v1.y); o[6] = f2bf(v1.z); o[7] = f2bf(v1.w);
        A[i] = o;
    }
}

// ---------------------------------------------------------------------------
// Kernel 2: FWHT each row of W (len 2048), scale 1/sqrt(2048), emit bf16.
// H symmetric+orthogonal: (xH/vn) W^T == x (W H/vn)^T.
// ---------------------------------------------------------------------------
__global__ void fwht_w_kernel(const float* __restrict__ W,
                              unsigned short* __restrict__ Bt) {
    const int n = 2048;
    __shared__ float buf[2048];
    const float* src = W + (size_t)blockIdx.x * n;
    for (int i = threadIdx.x; i < n; i += 256) buf[i] = src[i];
    __syncthreads();
    for (int len = 1; len < n; len <<= 1) {
        for (int j = threadIdx.x; j < n / 2; j += 256) {
            int idx = ((j & ~(len - 1)) << 1) | (j & (len - 1));
            float a = buf[idx], b = buf[idx + len];
            buf[idx]       = a + b;
            buf[idx + len] = a - b;
        }
        __syncthreads();
    }
    const float scale = 0.02209708691207961f; // 1/sqrt(2048)
    unsigned short* dst = Bt + (size_t)blockIdx.x * n;
    for (int i = threadIdx.x; i < n; i += 256) dst[i] = f2bf(buf[i] * scale);
}

// ---------------------------------------------------------------------------
// Kernel 3 (R6 resubmit — R2's bench was an infra failure, no signal):
// C[M][N] = A[M][K]*B[N][K]^T + bias, bf16 MFMA 16x16x32.
//
// R5 post-mortem: 4 lockstep barriers/tile serialized LDS-read time vs MFMA
// time (MfmaUtil 31%, 3500 cyc/tile vs 1024 MFMA-need). R6 keeps R5's
// proven parts — conflict-free XOR swizzle (BANK_CONFLICT 1.7e7 -> 0),
// 4-slab BK=32 ring, depth-3 prefetch with counted vmcnt(8) (never 0 in
// steady state), setprio around MFMA clusters — and drops to ONE s_barrier
// per 32-k tile so waves drift: one wave's MFMA overlaps other waves'
// ds_read/stage, and the compiler interleaves the af[4..7] reads under the
// first 16-MFMA cluster (no barrier in between).
//
// Correctness: (RAW) each wave's own 4 stage-loads for tile t+1 are
// confirmed by its vmcnt(8) before the tile-t-end barrier => slab visible
// to all waves after barrier. (WAR) a wave's ds_reads of tile t complete
// before its MFMAs (compiler lgkmcnt) hence before its barrier arrival;
// staging slab (t+3)&3 == (t-1)&3 is issued after that barrier.
// ---------------------------------------------------------------------------
constexpr int GK = 2048;       // K (fixed by problem)
constexpr int GN = 2048;       // N
constexpr int NT = GK / 32;    // 64 k-tiles

__global__ __launch_bounds__(512, 2) void had_gemm_kernel(
    const unsigned short* __restrict__ A,   // [M][K] bf16
    const unsigned short* __restrict__ B,   // [N][K] bf16 (W')
    const float* __restrict__ bias,         // [N]
    float* __restrict__ C)                  // [M][N] fp32
{
    __shared__ __attribute__((aligned(16))) unsigned short As[4][256 * 32];
    __shared__ __attribute__((aligned(16))) unsigned short Bs[4][256 * 32];

    const int tid  = threadIdx.x;
    const int lane = tid & 63;
    const int wave = tid >> 6;      // 0..7
    const int wm   = wave & 1;      // row half  (128 rows)
    const int wn   = wave >> 1;     // col quarter (64 cols)
    const int l16  = lane & 15;
    const int quad = lane >> 4;
    const int m0 = blockIdx.y * 256;
    const int n0 = blockIdx.x * 256;

    f32x4 acc[8][4] = {};

    // ---- staging geometry: inst i covers rows [i*128, i*128+128) of the
    // tile, thread -> row = i*128 + tid/4, 16B chunk (tid&3) of the 64B
    // k-slice. Source col pre-swizzled; LDS dest linear (wave base+lane*16).
    const int srow = tid >> 2;
    const int swzc = ((tid & 3) * 16) ^ (((srow >> 1) & 3) << 4);
    const char* gA0 = (const char*)(A + (size_t)(m0 + srow) * GK) + swzc;
    const char* gA1 = (const char*)(A + (size_t)(m0 + 128 + srow) * GK) + swzc;
    const char* gB0 = (const char*)(B + (size_t)(n0 + srow) * GK) + swzc;
    const char* gB1 = (const char*)(B + (size_t)(n0 + 128 + srow) * GK) + swzc;
    // ((srow+128)>>1)&3 == (srow>>1)&3, so swzc is valid for both insts.

#define STAGE_A(t_) { const int sl_ = (t_) & 3;                                   \
    __builtin_amdgcn_global_load_lds(                                             \
        (const __attribute__((address_space(1))) void*)(gA0 + (t_) * 64),         \
        (__attribute__((address_space(3))) void*)(&As[sl_][wave * 512]), 16, 0, 0);\
    __builtin_amdgcn_global_load_lds(                                             \
        (const __attribute__((address_space(1))) void*)(gA1 + (t_) * 64),         \
        (__attribute__((address_space(3))) void*)(&As[sl_][4096 + wave * 512]), 16, 0, 0); }
#define STAGE_B(t_) { const int sl_ = (t_) & 3;                                   \
    __builtin_amdgcn_global_load_lds(                                             \
        (const __attribute__((address_space(1))) void*)(gB0 + (t_) * 64),         \
        (__attribute__((address_space(3))) void*)(&Bs[sl_][wave * 512]), 16, 0, 0);\
    __builtin_amdgcn_global_load_lds(                                             \
        (const __attribute__((address_space(1))) void*)(gB1 + (t_) * 64),         \
        (__attribute__((address_space(3))) void*)(&Bs[sl_][4096 + wave * 512]), 16, 0, 0); }

    // ---- fragment read offsets (same XOR as staging source) ----
    const int arow = wm * 128 + l16;
    const int brow = wn * 64 + l16;
    const int sw   = ((l16 >> 1) & 3) << 4;   // row bits 1-2 come from l16
    const unsigned aoff = (unsigned)(arow * 64 + quad * 16) ^ sw;
    const unsigned boff = (unsigned)(brow * 64 + quad * 16) ^ sw;
    const char* sabase = (const char*)&As[0][0];
    const char* sbbase = (const char*)&Bs[0][0];

    // ---- prologue: stage tiles 0..2 (12 loads), confirm tile 0 ----
    STAGE_A(0) STAGE_B(0) asm volatile("" ::: "memory");
    STAGE_A(1) STAGE_B(1) asm volatile("" ::: "memory");
    STAGE_A(2) STAGE_B(2)
    asm volatile("s_waitcnt vmcnt(8)" ::: "memory");   // oldest 4 = tile 0 done
    __builtin_amdgcn_s_barrier();
    asm volatile("" ::: "memory");

    for (int t = 0; t < NT; ++t) {
        const char* sa = sabase + (size_t)(t & 3) * 16384;
        const char* sb = sbbase + (size_t)(t & 3) * 16384;
        bf16x8 af[8], bfr[4];

        // stage next A early (VMEM queue fills while we read/compute)
        if (t + 3 < NT) STAGE_A(t + 3);

        #pragma unroll
        for (int j = 0; j < 4; ++j)
            bfr[j] = *(const bf16x8*)(sb + (boff + j * 1024u));
        #pragma unroll
        for (int i = 0; i < 4; ++i)
            af[i] = *(const bf16x8*)(sa + (aoff + i * 1024u));

        __builtin_amdgcn_s_setprio(1);
        #pragma unroll
        for (int i = 0; i < 4; ++i)
            #pragma unroll
            for (int j = 0; j < 4; ++j)
                acc[i][j] = __builtin_amdgcn_mfma_f32_16x16x32_bf16(
                    af[i], bfr[j], acc[i][j], 0, 0, 0);
        __builtin_amdgcn_s_setprio(0);

        // stage next B mid-tile; second half of A-frag reads can issue
        // under the first MFMA cluster (no barrier in between).
        if (t + 3 < NT) STAGE_B(t + 3);
        #pragma unroll
        for (int i = 0; i < 4; ++i)
            af[4 + i] = *(const bf16x8*)(sa + (aoff + (4 + i) * 1024u));

        __builtin_amdgcn_s_setprio(1);
        #pragma unroll
        for (int i = 0; i < 4; ++i)
            #pragma unroll
            for (int j = 0; j < 4; ++j)
                acc[4 + i][j] = __builtin_amdgcn_mfma_f32_16x16x32_bf16(
                    af[4 + i], bfr[j], acc[4 + i][j], 0, 0, 0);
        __builtin_amdgcn_s_setprio(0);

        // tile end: counted wait (tile t+1 confirmed; t+2/t+3 stay in flight)
        if (t < NT - 3)       { asm volatile("s_waitcnt vmcnt(8)" ::: "memory"); }
        else if (t == NT - 3) { asm volatile("s_waitcnt vmcnt(4)" ::: "memory"); }
        else if (t == NT - 2) { asm volatile("s_waitcnt vmcnt(0)" ::: "memory"); }
        __builtin_amdgcn_s_barrier();
        asm volatile("" ::: "memory");
    }
#undef STAGE_A
#undef STAGE_B

    // ---- epilogue: C/D layout col=lane&15, row=quad*4+reg (m89-verified) ----
    float bv[4];
    #pragma unroll
    for (int j = 0; j < 4; ++j) bv[j] = bias[n0 + wn * 64 + j * 16 + l16];

    #pragma unroll
    for (int i = 0; i < 8; ++i) {
        #pragma unroll
        for (int r = 0; r < 4; ++r) {
            int row = m0 + wm * 128 + i * 16 + quad * 4 + r;
            float* cp = C + (size_t)row * GN + (n0 + wn * 64 + l16);
            #pragma unroll
            for (int j = 0; j < 4; ++j)
                cp[j * 16] = acc[i][j][r] + bv[j];
        }
    }
}

// ---------------------------------------------------------------------------
extern "C" void kernel_launch(void* const* d_in, const int* in_sizes, int n_in,
                              void* d_out, int out_size, void* d_ws, size_t ws_size,
                              hipStream_t stream) {
    const float* x = (const float*)d_in[0];  // [4,4096,2048] fp32
    const float* W = (const float*)d_in[1];  // [2048,2048]  fp32
    const float* b = (const float*)d_in[2];  // [2048]       fp32
    float* out = (float*)d_out;              // [4,4096,2048] fp32

    const int d = in_sizes[2];          // 2048
    const int M = in_sizes[0] / d;      // 16384
    const int N = d, K = d;

    // Workspace: A bf16 [M][K] (64 MB) + W' bf16 [N][K] (8 MB)
    unsigned short* A_ws  = (unsigned short*)d_ws;
    unsigned short* Bt_ws = A_ws + (size_t)M * K;

    int n8 = in_sizes[0] / 8;
    cast_x_kernel<<<(n8 + 255) / 256, 256, 0, stream>>>(
        (const float4*)x, (u16x8*)A_ws, n8);

    fwht_w_kernel<<<N, 256, 0, stream>>>(W, Bt_ws);

    dim3 grid(N / 256, M / 256);  // (8, 64) = 512 blocks
    had_gemm_kernel<<<grid, 512, 0, stream>>>(A_ws, Bt_ws, b, out);
}